// Round 8
// baseline (262.473 us; speedup 1.0000x reference)
//
#include <hip/hip_runtime.h>
#include <math.h>

#define DIM 160
#define NB 2
#define CHUNK 10
#define NCHZ (DIM / CHUNK)   // 16
#define NTHREADS 256
#define EPS_F 1.1920928955078125e-07f

// Staged-plane geometry: 32x32 xy tile per block.
#define CW 10                 // 16B chunks per region row (40 floats: 4+32+4)
#define RH 34                 // region rows (1+32+1)
#define LS 44                 // LDS row stride in floats (44%32=12 -> bank spread; 16B-aligned)
#define PLANE_F (RH * LS)     // 1496 floats per image plane in LDS
#define NCK (2 * RH * CW)     // 680 staged chunks per plane-step (both images)

typedef float v4f __attribute__((ext_vector_type(4)));

__device__ __forceinline__ int imin(int a, int b) { return a < b ? a : b; }
__device__ __forceinline__ int imax(int a, int b) { return a > b ? a : b; }

// ws layout (doubles):
// [0..1] sum_mask[n], [2..3] sum_norm_pred[n], [4..5] sum_norm_tgt[n],
// [6] sum inner^2, [8..9] c_pred[n], [10..11] c_tgt[n]

// Per-slot staging descriptors (loop-invariant; computed once per block).
struct Slot {
  const float* srcb;  // image base + yc*DIM + xc  (add zc*DIM*DIM per step)
  int ldsoff;         // img*PLANE_F + row*LS + 4*ch
  bool act;
};

__device__ __forceinline__ void make_slots(const float* __restrict__ pb,
                                           const float* __restrict__ tb,
                                           int x0, int y0, int tid, Slot (&sl)[3]) {
#pragma unroll
  for (int s = 0; s < 3; ++s) {
    const int i = tid + NTHREADS * s;
    sl[s].act = (i < NCK);
    const int ii = sl[s].act ? i : 0;
    const int img = ii / (RH * CW);
    const int rem = ii - img * (RH * CW);
    const int row = rem / CW, ch = rem - row * CW;
    const int yc = imin(imax(y0 - 1 + row, 0), DIM - 1);
    const int xc = imin(imax(x0 - 4 + 4 * ch, 0), DIM - 4);
    sl[s].srcb = (img ? tb : pb) + yc * DIM + xc;
    sl[s].ldsoff = img * PLANE_F + row * LS + 4 * ch;
  }
}

__device__ __forceinline__ void stage_load(const Slot (&sl)[3], int z, v4f (&r)[3]) {
  const int zoff = imin(imax(z, 0), DIM - 1) * DIM * DIM;
#pragma unroll
  for (int s = 0; s < 3; ++s)
    if (sl[s].act) r[s] = *(const v4f*)(sl[s].srcb + zoff);
}

__device__ __forceinline__ void stage_write(float* __restrict__ buf,
                                            const Slot (&sl)[3], const v4f (&r)[3]) {
#pragma unroll
  for (int s = 0; s < 3; ++s)
    if (sl[s].act) *(v4f*)(buf + sl[s].ldsoff) = r[s];
}

// P1 = diff_x*smooth_y, P2 = smooth_x*diff_y, P3 = smooth_x*smooth_y for 4 voxels,
// read from one image's LDS plane. rf* are row-valid flags (include z flag);
// fxl/fxr zero the x halo taps.
__device__ __forceinline__ void compute_P_lds(const float* __restrict__ pl,
                                              int tx, int ty,
                                              float rf0, float rf1, float rf2,
                                              float fxl, float fxr,
                                              float (&P1)[4], float (&P2)[4], float (&P3)[4]) {
#pragma unroll
  for (int rr = 0; rr < 3; ++rr) {
    const float rf = (rr == 0) ? rf0 : (rr == 1) ? rf1 : rf2;
    const float* row = pl + (ty + rr) * LS + 4 * tx;
    const v4f L = *(const v4f*)row;        // need L.w  (col x-1 of voxel 0)
    const v4f M = *(const v4f*)(row + 4);  // cols of the 4 voxels
    const v4f R = *(const v4f*)(row + 8);  // need R.x  (col x+1 of voxel 3)
    const float fm1 = L.w * fxl, f0 = M.x, f1 = M.y, f2 = M.z, f3 = M.w, f4 = R.x * fxr;
    float S[4], D[4];
    S[0] = (fm1 + 2.f * f0 + f1) * rf;  D[0] = (f1 - fm1) * rf;
    S[1] = (f0 + 2.f * f1 + f2) * rf;   D[1] = (f2 - f0) * rf;
    S[2] = (f1 + 2.f * f2 + f3) * rf;   D[2] = (f3 - f1) * rf;
    S[3] = (f2 + 2.f * f3 + f4) * rf;   D[3] = (f4 - f2) * rf;
    if (rr == 0) {
#pragma unroll
      for (int j = 0; j < 4; ++j) { P1[j] = D[j]; P2[j] = -S[j]; P3[j] = S[j]; }
    } else if (rr == 1) {
#pragma unroll
      for (int j = 0; j < 4; ++j) { P1[j] += 2.f * D[j]; P3[j] += 2.f * S[j]; }
    } else {
#pragma unroll
      for (int j = 0; j < 4; ++j) { P1[j] += D[j]; P2[j] += S[j]; P3[j] += S[j]; }
    }
  }
}

__global__ __launch_bounds__(NTHREADS, 2)
void pass1_kernel(const float* __restrict__ pred, const float* __restrict__ tgt,
                  const float* __restrict__ mask, double* __restrict__ ws) {
  __shared__ float lds[2][2 * PLANE_F];
  __shared__ float red[3][4];
  const int tid = threadIdx.x;
  const int tx = tid & 7, ty = tid >> 3;
  const int n = blockIdx.z / NCHZ;
  const int zs = (blockIdx.z % NCHZ) * CHUNK;
  const int x0 = blockIdx.x * 32, y0 = blockIdx.y * 32;
  const size_t base = (size_t)n * DIM * DIM * DIM;
  const float* pb = pred + base;
  const float* tb = tgt + base;
  const float* mb = mask + base;
  const int x = x0 + 4 * tx, y = y0 + ty;

  const float fxl = (x > 0) ? 1.f : 0.f;
  const float fxr = (x + 4 < DIM) ? 1.f : 0.f;
  const float fym = (y > 0) ? 1.f : 0.f;
  const float fyp = (y < DIM - 1) ? 1.f : 0.f;

  Slot sl[3];
  make_slots(pb, tb, x0, y0, tid, sl);

  float OUT[2][2][3][4];  // [slot][img][field][j]
#pragma unroll
  for (int s = 0; s < 2; ++s)
#pragma unroll
    for (int g = 0; g < 2; ++g)
#pragma unroll
      for (int f = 0; f < 3; ++f)
#pragma unroll
        for (int j = 0; j < 4; ++j) OUT[s][g][f][j] = 0.f;

  float am = 0.f, anp = 0.f, ant = 0.f;
  v4f stg[3];

  stage_load(sl, zs - 1, stg);
  stage_write(lds[0], sl, stg);
  __syncthreads();

#pragma unroll
  for (int i = 0; i <= CHUNK + 1; ++i) {
    const int z = zs - 1 + i;
    if (i <= CHUNK) stage_load(sl, zs + i, stg);  // next plane into regs (in flight)

    const float fz = ((unsigned)z < DIM) ? 1.f : 0.f;
    const float* bufb = lds[i & 1];
    float P[2][3][4];
    compute_P_lds(bufb, tx, ty, fz * fym, fz, fz * fyp, fxl, fxr,
                  P[0][0], P[0][1], P[0][2]);
    compute_P_lds(bufb + PLANE_F, tx, ty, fz * fym, fz, fz * fyp, fxl, fxr,
                  P[1][0], P[1][1], P[1][2]);

    const int sA = i & 1, sB = sA ^ 1;
    if (i >= 2) {
      const int zo = z - 1;
      const v4f mv = *(const v4f*)(mb + (zo * DIM + y) * DIM + x);
#pragma unroll
      for (int j = 0; j < 4; ++j) {
        const float mj = (j == 0) ? mv.x : (j == 1) ? mv.y : (j == 2) ? mv.z : mv.w;
        float gpx = OUT[sA][0][0][j] + P[0][0][j];
        float gpy = OUT[sA][0][1][j] + P[0][1][j];
        float gpz = OUT[sA][0][2][j] + P[0][2][j];
        float gtx = OUT[sA][1][0][j] + P[1][0][j];
        float gty = OUT[sA][1][1][j] + P[1][1][j];
        float gtz = OUT[sA][1][2][j] + P[1][2][j];
        am += mj;
        anp += sqrtf(gpx * gpx + gpy * gpy + gpz * gpz + EPS_F) * mj;
        ant += sqrtf(gtx * gtx + gty * gty + gtz * gtz + EPS_F) * mj;
      }
    }
#pragma unroll
    for (int g = 0; g < 2; ++g)
#pragma unroll
      for (int j = 0; j < 4; ++j) {
        OUT[sA][g][0][j] = P[g][0][j];
        OUT[sA][g][1][j] = P[g][1][j];
        OUT[sA][g][2][j] = -P[g][2][j];
        OUT[sB][g][0][j] += 2.f * P[g][0][j];
        OUT[sB][g][1][j] += 2.f * P[g][1][j];
      }

    if (i <= CHUNK) {
      __syncthreads();                       // all waves done reading buf[i&1^1]
      stage_write(lds[(i & 1) ^ 1], sl, stg);  // land next plane
      __syncthreads();                       // next plane visible to all
    }
  }

  float v0 = am, v1 = anp, v2 = ant;
#pragma unroll
  for (int off = 32; off > 0; off >>= 1) {
    v0 += __shfl_down(v0, off, 64);
    v1 += __shfl_down(v1, off, 64);
    v2 += __shfl_down(v2, off, 64);
  }
  const int lane = tid & 63, wave = tid >> 6;
  if (lane == 0) { red[0][wave] = v0; red[1][wave] = v1; red[2][wave] = v2; }
  __syncthreads();
  if (tid == 0) {
    atomicAdd(&ws[0 + n], (double)(red[0][0] + red[0][1] + red[0][2] + red[0][3]));
    atomicAdd(&ws[2 + n], (double)(red[1][0] + red[1][1] + red[1][2] + red[1][3]));
    atomicAdd(&ws[4 + n], (double)(red[2][0] + red[2][1] + red[2][2] + red[2][3]));
  }
}

__global__ void compute_c_kernel(double* __restrict__ ws) {
  if (threadIdx.x == 0 && blockIdx.x == 0) {
    for (int n = 0; n < NB; ++n) {
      double inv_m = 1.0 / ws[0 + n];
      double ae_p = ws[2 + n] * inv_m;  // eta = 1.0
      double ae_t = ws[4 + n] * inv_m;
      ws[8 + n] = ae_p * ae_p + (double)EPS_F;
      ws[10 + n] = ae_t * ae_t + (double)EPS_F;
    }
  }
}

__global__ __launch_bounds__(NTHREADS, 2)
void pass2_kernel(const float* __restrict__ pred, const float* __restrict__ tgt,
                  double* __restrict__ ws) {
  __shared__ float lds[2][2 * PLANE_F];
  __shared__ float red[4];
  const int tid = threadIdx.x;
  const int tx = tid & 7, ty = tid >> 3;
  const int n = blockIdx.z / NCHZ;
  const int zs = (blockIdx.z % NCHZ) * CHUNK;
  const int x0 = blockIdx.x * 32, y0 = blockIdx.y * 32;
  const size_t base = (size_t)n * DIM * DIM * DIM;
  const float* pb = pred + base;
  const float* tb = tgt + base;

  const float cp = (float)ws[8 + n];
  const float ct = (float)ws[10 + n];

  const int x = x0 + 4 * tx, y = y0 + ty;
  const float fxl = (x > 0) ? 1.f : 0.f;
  const float fxr = (x + 4 < DIM) ? 1.f : 0.f;
  const float fym = (y > 0) ? 1.f : 0.f;
  const float fyp = (y < DIM - 1) ? 1.f : 0.f;

  Slot sl[3];
  make_slots(pb, tb, x0, y0, tid, sl);

  float OUT[2][2][3][4];
#pragma unroll
  for (int s = 0; s < 2; ++s)
#pragma unroll
    for (int g = 0; g < 2; ++g)
#pragma unroll
      for (int f = 0; f < 3; ++f)
#pragma unroll
        for (int j = 0; j < 4; ++j) OUT[s][g][f][j] = 0.f;

  float acc = 0.f;
  v4f stg[3];

  stage_load(sl, zs - 1, stg);
  stage_write(lds[0], sl, stg);
  __syncthreads();

#pragma unroll
  for (int i = 0; i <= CHUNK + 1; ++i) {
    const int z = zs - 1 + i;
    if (i <= CHUNK) stage_load(sl, zs + i, stg);

    const float fz = ((unsigned)z < DIM) ? 1.f : 0.f;
    const float* bufb = lds[i & 1];
    float P[2][3][4];
    compute_P_lds(bufb, tx, ty, fz * fym, fz, fz * fyp, fxl, fxr,
                  P[0][0], P[0][1], P[0][2]);
    compute_P_lds(bufb + PLANE_F, tx, ty, fz * fym, fz, fz * fyp, fxl, fxr,
                  P[1][0], P[1][1], P[1][2]);

    const int sA = i & 1, sB = sA ^ 1;
    if (i >= 2) {
#pragma unroll
      for (int j = 0; j < 4; ++j) {
        float gpx = OUT[sA][0][0][j] + P[0][0][j];
        float gpy = OUT[sA][0][1][j] + P[0][1][j];
        float gpz = OUT[sA][0][2][j] + P[0][2][j];
        float gtx = OUT[sA][1][0][j] + P[1][0][j];
        float gty = OUT[sA][1][1][j] + P[1][1][j];
        float gtz = OUT[sA][1][2][j] + P[1][2][j];
        float sqp = gpx * gpx + gpy * gpy + gpz * gpz;
        float sqt = gtx * gtx + gty * gty + gtz * gtz;
        float dot = gpx * gtx + gpy * gty + gpz * gtz;
        float inner = dot * rsqrtf((sqp + cp) * (sqt + ct));
        acc += inner * inner;
      }
    }
#pragma unroll
    for (int g = 0; g < 2; ++g)
#pragma unroll
      for (int j = 0; j < 4; ++j) {
        OUT[sA][g][0][j] = P[g][0][j];
        OUT[sA][g][1][j] = P[g][1][j];
        OUT[sA][g][2][j] = -P[g][2][j];
        OUT[sB][g][0][j] += 2.f * P[g][0][j];
        OUT[sB][g][1][j] += 2.f * P[g][1][j];
      }

    if (i <= CHUNK) {
      __syncthreads();
      stage_write(lds[(i & 1) ^ 1], sl, stg);
      __syncthreads();
    }
  }

#pragma unroll
  for (int off = 32; off > 0; off >>= 1) acc += __shfl_down(acc, off, 64);
  const int lane = tid & 63, wave = tid >> 6;
  if (lane == 0) red[wave] = acc;
  __syncthreads();
  if (tid == 0) atomicAdd(&ws[6], (double)(red[0] + red[1] + red[2] + red[3]));
}

__global__ void finalize_kernel(const double* __restrict__ ws, float* __restrict__ out) {
  if (threadIdx.x == 0 && blockIdx.x == 0) {
    double mean = ws[6] / ((double)NB * DIM * DIM * DIM);
    out[0] = (float)(1.0 - mean);
  }
}

extern "C" void kernel_launch(void* const* d_in, const int* in_sizes, int n_in,
                              void* d_out, int out_size, void* d_ws, size_t ws_size,
                              hipStream_t stream) {
  const float* pred = (const float*)d_in[0];
  const float* tgt = (const float*)d_in[1];
  const float* mask = (const float*)d_in[2];
  float* out = (float*)d_out;
  double* ws = (double*)d_ws;

  hipMemsetAsync(d_ws, 0, 16 * sizeof(double), stream);

  dim3 grid(DIM / 32, DIM / 32, NCHZ * NB);  // 5 x 5 x 32 = 800 blocks
  pass1_kernel<<<grid, NTHREADS, 0, stream>>>(pred, tgt, mask, ws);
  compute_c_kernel<<<1, 64, 0, stream>>>(ws);
  pass2_kernel<<<grid, NTHREADS, 0, stream>>>(pred, tgt, ws);
  finalize_kernel<<<1, 64, 0, stream>>>(ws, out);
}

// Round 9
// 146.172 us; speedup vs baseline: 1.7957x; 1.7957x over previous
//
#include <hip/hip_runtime.h>
#include <math.h>

#define DIM 160
#define NB 2
#define CHUNK 5
#define NCHZ (DIM / CHUNK)   // 32
#define NTHREADS 256
#define EPS_F 1.1920928955078125e-07f

typedef float v4f __attribute__((ext_vector_type(4)));

// Compile-time scheduler fence: nothing moves across (rule #18). Loads issued
// before it cannot sink into the compute region after it, so a full plane
// stays in flight; s_waitcnt insertion remains compiler-owned (safe).
#define SBAR() __builtin_amdgcn_sched_barrier(0)

__device__ __forceinline__ int imin(int a, int b) { return a < b ? a : b; }
__device__ __forceinline__ int imax(int a, int b) { return a > b ? a : b; }

// ws layout (doubles):
// [0..1] sum_mask[n], [2..3] sum_norm_pred[n], [4..5] sum_norm_tgt[n],
// [6] sum inner^2, [8..9] c_pred[n], [10..11] c_tgt[n]

// Issue one plane's 9 aligned float4 loads (rows y-1,y,y+1 x {L,M,R}).
// Addresses clamped (always legal); edge contributions zeroed at compute time.
__device__ __forceinline__ void issue_plane(const float* __restrict__ img, int zoff,
                                            int ro0, int ro1, int ro2,
                                            int xL, int xM, int xR, v4f (&B)[9]) {
  const float* r0 = img + zoff + ro0;
  const float* r1 = img + zoff + ro1;
  const float* r2 = img + zoff + ro2;
  B[0] = *(const v4f*)(r0 + xL); B[1] = *(const v4f*)(r0 + xM); B[2] = *(const v4f*)(r0 + xR);
  B[3] = *(const v4f*)(r1 + xL); B[4] = *(const v4f*)(r1 + xM); B[5] = *(const v4f*)(r1 + xR);
  B[6] = *(const v4f*)(r2 + xL); B[7] = *(const v4f*)(r2 + xM); B[8] = *(const v4f*)(r2 + xR);
}

// P1 = diff_x*smooth_y, P2 = smooth_x*diff_y, P3 = smooth_x*smooth_y for 4 voxels.
// rf* are row-valid flags (include z flag); fxl/fxr zero the x halo taps.
// (Flag-zeroing + clamped loads validated in round 8.)
__device__ __forceinline__ void compute_P(const v4f (&B)[9],
                                          float rf0, float rf1, float rf2,
                                          float fxl, float fxr,
                                          float (&P1)[4], float (&P2)[4], float (&P3)[4]) {
#pragma unroll
  for (int r = 0; r < 3; ++r) {
    const float rf = (r == 0) ? rf0 : (r == 1) ? rf1 : rf2;
    const v4f L = B[r * 3 + 0], M = B[r * 3 + 1], R = B[r * 3 + 2];
    const float fm1 = L.w * fxl, f0 = M.x, f1 = M.y, f2 = M.z, f3 = M.w, f4 = R.x * fxr;
    float S[4], D[4];
    S[0] = (fm1 + 2.f * f0 + f1) * rf;  D[0] = (f1 - fm1) * rf;
    S[1] = (f0 + 2.f * f1 + f2) * rf;   D[1] = (f2 - f0) * rf;
    S[2] = (f1 + 2.f * f2 + f3) * rf;   D[2] = (f3 - f1) * rf;
    S[3] = (f2 + 2.f * f3 + f4) * rf;   D[3] = (f4 - f2) * rf;
    if (r == 0) {
#pragma unroll
      for (int j = 0; j < 4; ++j) { P1[j] = D[j]; P2[j] = -S[j]; P3[j] = S[j]; }
    } else if (r == 1) {
#pragma unroll
      for (int j = 0; j < 4; ++j) { P1[j] += 2.f * D[j]; P3[j] += 2.f * S[j]; }
    } else {
#pragma unroll
      for (int j = 0; j < 4; ++j) { P1[j] += D[j]; P2[j] += S[j]; P3[j] += S[j]; }
    }
  }
}

// One image per block (im = 0 pred [+mask], 1 tgt). Pending-output z-recurrence
// (validated R5): processing plane z finalizes out[z-1], seeds out[z], out[z+1].
__global__ __launch_bounds__(NTHREADS)
void pass1_kernel(const float* __restrict__ pred, const float* __restrict__ tgt,
                  const float* __restrict__ mask, double* __restrict__ ws) {
  __shared__ float red[2][4];
  const int tid = threadIdx.x;
  const int tx = tid & 7, ty = tid >> 3;
  int bz = blockIdx.z;
  const int im = bz & 1; bz >>= 1;
  const int n = bz / NCHZ;
  const int zs = (bz % NCHZ) * CHUNK;
  const int xb = blockIdx.x * 32 + tx * 4;
  const int y = blockIdx.y * 32 + ty;
  const size_t base = (size_t)n * DIM * DIM * DIM;
  const float* img = (im == 0 ? pred : tgt) + base;
  const float* mb = mask + base;

  const float fxl = (xb >= 4) ? 1.f : 0.f;
  const float fxr = (xb + 4 < DIM) ? 1.f : 0.f;
  const float fym = (y >= 1) ? 1.f : 0.f;
  const float fyp = (y <= DIM - 2) ? 1.f : 0.f;

  // Loop-invariant row/col offsets (clamped).
  const int ro0 = imax(y - 1, 0) * DIM;
  const int ro1 = y * DIM;
  const int ro2 = imin(y + 1, DIM - 1) * DIM;
  const int xL = imax(xb - 4, 0), xM = xb, xR = imin(xb + 4, DIM - 4);

  float OUT[2][3][4];
#pragma unroll
  for (int s = 0; s < 2; ++s)
#pragma unroll
    for (int f = 0; f < 3; ++f)
#pragma unroll
      for (int j = 0; j < 4; ++j) OUT[s][f][j] = 0.f;

  float am = 0.f, an = 0.f;
  v4f BUF[2][9];          // ping-pong plane buffers (static idx under full unroll)
  v4f MV[2];              // ping-pong mask prefetch
  MV[0] = (v4f)(0.f); MV[1] = (v4f)(0.f);

  issue_plane(img, imin(imax(zs - 1, 0), DIM - 1) * DIM * DIM,
              ro0, ro1, ro2, xL, xM, xR, BUF[0]);

#pragma unroll
  for (int i = 0; i <= CHUNK + 1; ++i) {
    const int z = zs - 1 + i;
    // ---- issue phase: next plane (+ mask) into the other buffer ----
    if (i <= CHUNK)
      issue_plane(img, imin(zs + i, DIM - 1) * DIM * DIM,
                  ro0, ro1, ro2, xL, xM, xR, BUF[(i + 1) & 1]);
    if (im == 0 && i >= 1 && i <= CHUNK)
      MV[(i + 1) & 1] = *(const v4f*)(mb + ((zs + i - 1) * DIM + y) * DIM + xb);
    SBAR();
    // ---- compute phase: current plane (loads issued last iteration) ----
    const float fz = ((unsigned)z < DIM) ? 1.f : 0.f;
    float P1a[4], P2a[4], P3a[4];
    compute_P(BUF[i & 1], fz * fym, fz, fz * fyp, fxl, fxr, P1a, P2a, P3a);
    const int sA = i & 1, sB = sA ^ 1;
    if (i >= 2) {
      if (im == 0) {
        const v4f mv = MV[i & 1];
#pragma unroll
        for (int j = 0; j < 4; ++j) {
          const float mj = (j == 0) ? mv.x : (j == 1) ? mv.y : (j == 2) ? mv.z : mv.w;
          float gx = OUT[sA][0][j] + P1a[j];
          float gy = OUT[sA][1][j] + P2a[j];
          float gz = OUT[sA][2][j] + P3a[j];
          am += mj;
          an += sqrtf(gx * gx + gy * gy + gz * gz + EPS_F) * mj;
        }
      } else {
#pragma unroll
        for (int j = 0; j < 4; ++j) {
          float gx = OUT[sA][0][j] + P1a[j];
          float gy = OUT[sA][1][j] + P2a[j];
          float gz = OUT[sA][2][j] + P3a[j];
          an += sqrtf(gx * gx + gy * gy + gz * gz + EPS_F);
        }
      }
    }
#pragma unroll
    for (int j = 0; j < 4; ++j) {
      OUT[sA][0][j] = P1a[j];
      OUT[sA][1][j] = P2a[j];
      OUT[sA][2][j] = -P3a[j];
      OUT[sB][0][j] += 2.f * P1a[j];
      OUT[sB][1][j] += 2.f * P2a[j];
    }
  }

  float v0 = am, v1 = an;
#pragma unroll
  for (int off = 32; off > 0; off >>= 1) {
    v0 += __shfl_down(v0, off, 64);
    v1 += __shfl_down(v1, off, 64);
  }
  const int lane = tid & 63, wave = tid >> 6;
  if (lane == 0) { red[0][wave] = v0; red[1][wave] = v1; }
  __syncthreads();
  if (tid == 0) {
    if (im == 0) atomicAdd(&ws[0 + n], (double)(red[0][0] + red[0][1] + red[0][2] + red[0][3]));
    atomicAdd(&ws[2 + 2 * im + n], (double)(red[1][0] + red[1][1] + red[1][2] + red[1][3]));
  }
}

__global__ void compute_c_kernel(double* __restrict__ ws) {
  if (threadIdx.x == 0 && blockIdx.x == 0) {
    for (int n = 0; n < NB; ++n) {
      double inv_m = 1.0 / ws[0 + n];
      double ae_p = ws[2 + n] * inv_m;  // eta = 1.0
      double ae_t = ws[4 + n] * inv_m;
      ws[8 + n] = ae_p * ae_p + (double)EPS_F;
      ws[10 + n] = ae_t * ae_t + (double)EPS_F;
    }
  }
}

__global__ __launch_bounds__(NTHREADS)
void pass2_kernel(const float* __restrict__ pred, const float* __restrict__ tgt,
                  double* __restrict__ ws) {
  __shared__ float red[4];
  const int tid = threadIdx.x;
  const int tx = tid & 7, ty = tid >> 3;
  const int bz = blockIdx.z;
  const int n = bz / NCHZ;
  const int zs = (bz % NCHZ) * CHUNK;
  const int xb = blockIdx.x * 32 + tx * 4;
  const int y = blockIdx.y * 32 + ty;
  const size_t base = (size_t)n * DIM * DIM * DIM;
  const float* pb = pred + base;
  const float* tb = tgt + base;

  const float cp = (float)ws[8 + n];
  const float ct = (float)ws[10 + n];

  const float fxl = (xb >= 4) ? 1.f : 0.f;
  const float fxr = (xb + 4 < DIM) ? 1.f : 0.f;
  const float fym = (y >= 1) ? 1.f : 0.f;
  const float fyp = (y <= DIM - 2) ? 1.f : 0.f;

  const int ro0 = imax(y - 1, 0) * DIM;
  const int ro1 = y * DIM;
  const int ro2 = imin(y + 1, DIM - 1) * DIM;
  const int xL = imax(xb - 4, 0), xM = xb, xR = imin(xb + 4, DIM - 4);

  float OUT[2][2][3][4];  // [slot][img][field][j]
#pragma unroll
  for (int s = 0; s < 2; ++s)
#pragma unroll
    for (int g = 0; g < 2; ++g)
#pragma unroll
      for (int f = 0; f < 3; ++f)
#pragma unroll
        for (int j = 0; j < 4; ++j) OUT[s][g][f][j] = 0.f;

  float acc = 0.f;
  v4f PBUF[9], TBUF[9];  // one buffer per image; reissued right after consumption

  {
    const int z0off = imin(imax(zs - 1, 0), DIM - 1) * DIM * DIM;
    issue_plane(pb, z0off, ro0, ro1, ro2, xL, xM, xR, PBUF);
    issue_plane(tb, z0off, ro0, ro1, ro2, xL, xM, xR, TBUF);
  }

#pragma unroll
  for (int i = 0; i <= CHUNK + 1; ++i) {
    const int z = zs - 1 + i;
    const float fz = ((unsigned)z < DIM) ? 1.f : 0.f;
    const int znoff = imin(zs + i, DIM - 1) * DIM * DIM;

    // consume pred plane i (tgt's 9 loads still outstanding), reissue pred i+1
    float Pp1[4], Pp2[4], Pp3[4];
    compute_P(PBUF, fz * fym, fz, fz * fyp, fxl, fxr, Pp1, Pp2, Pp3);
    if (i <= CHUNK) issue_plane(pb, znoff, ro0, ro1, ro2, xL, xM, xR, PBUF);
    SBAR();
    // consume tgt plane i (pred i+1 in flight), reissue tgt i+1
    float Pt1[4], Pt2[4], Pt3[4];
    compute_P(TBUF, fz * fym, fz, fz * fyp, fxl, fxr, Pt1, Pt2, Pt3);
    if (i <= CHUNK) issue_plane(tb, znoff, ro0, ro1, ro2, xL, xM, xR, TBUF);
    SBAR();

    const int sA = i & 1, sB = sA ^ 1;
    if (i >= 2) {
#pragma unroll
      for (int j = 0; j < 4; ++j) {
        float gpx = OUT[sA][0][0][j] + Pp1[j];
        float gpy = OUT[sA][0][1][j] + Pp2[j];
        float gpz = OUT[sA][0][2][j] + Pp3[j];
        float gtx = OUT[sA][1][0][j] + Pt1[j];
        float gty = OUT[sA][1][1][j] + Pt2[j];
        float gtz = OUT[sA][1][2][j] + Pt3[j];
        float sqp = gpx * gpx + gpy * gpy + gpz * gpz;
        float sqt = gtx * gtx + gty * gty + gtz * gtz;
        float dot = gpx * gtx + gpy * gty + gpz * gtz;
        float inner = dot * rsqrtf((sqp + cp) * (sqt + ct));
        acc += inner * inner;
      }
    }
#pragma unroll
    for (int j = 0; j < 4; ++j) {
      OUT[sA][0][0][j] = Pp1[j];
      OUT[sA][0][1][j] = Pp2[j];
      OUT[sA][0][2][j] = -Pp3[j];
      OUT[sB][0][0][j] += 2.f * Pp1[j];
      OUT[sB][0][1][j] += 2.f * Pp2[j];
      OUT[sA][1][0][j] = Pt1[j];
      OUT[sA][1][1][j] = Pt2[j];
      OUT[sA][1][2][j] = -Pt3[j];
      OUT[sB][1][0][j] += 2.f * Pt1[j];
      OUT[sB][1][1][j] += 2.f * Pt2[j];
    }
  }

#pragma unroll
  for (int off = 32; off > 0; off >>= 1) acc += __shfl_down(acc, off, 64);
  const int lane = tid & 63, wave = tid >> 6;
  if (lane == 0) red[wave] = acc;
  __syncthreads();
  if (tid == 0) atomicAdd(&ws[6], (double)(red[0] + red[1] + red[2] + red[3]));
}

__global__ void finalize_kernel(const double* __restrict__ ws, float* __restrict__ out) {
  if (threadIdx.x == 0 && blockIdx.x == 0) {
    double mean = ws[6] / ((double)NB * DIM * DIM * DIM);
    out[0] = (float)(1.0 - mean);
  }
}

extern "C" void kernel_launch(void* const* d_in, const int* in_sizes, int n_in,
                              void* d_out, int out_size, void* d_ws, size_t ws_size,
                              hipStream_t stream) {
  const float* pred = (const float*)d_in[0];
  const float* tgt = (const float*)d_in[1];
  const float* mask = (const float*)d_in[2];
  float* out = (float*)d_out;
  double* ws = (double*)d_ws;

  hipMemsetAsync(d_ws, 0, 16 * sizeof(double), stream);

  dim3 grid1(DIM / 32, DIM / 32, NCHZ * NB * 2);  // 5 x 5 x 128 = 3200 blocks
  pass1_kernel<<<grid1, NTHREADS, 0, stream>>>(pred, tgt, mask, ws);
  compute_c_kernel<<<1, 64, 0, stream>>>(ws);
  dim3 grid2(DIM / 32, DIM / 32, NCHZ * NB);      // 5 x 5 x 64 = 1600 blocks
  pass2_kernel<<<grid2, NTHREADS, 0, stream>>>(pred, tgt, ws);
  finalize_kernel<<<1, 64, 0, stream>>>(ws, out);
}